// Round 2
// baseline (490.790 us; speedup 1.0000x reference)
//
#include <hip/hip_runtime.h>

#define N_TOK 2048
#define DMODEL 1024
#define NEXP 8
#define FFDIM 4096
#define NMAX 2048
#define ROWS 4096
#define ROWS_PAD 4224

#define BM 128
#define BN 128
#define BK 64
#define MT_MAX 16
#define KSPL 4

typedef __attribute__((ext_vector_type(8))) short s16x8;
typedef __attribute__((ext_vector_type(4))) float f32x4;

__device__ __forceinline__ float bf2f(ushort u) {
    union { uint i; float f; } x; x.i = ((uint)u) << 16; return x.f;
}
__device__ __forceinline__ ushort f2bf(float f) {
    union { float f; uint i; } x; x.f = f;
    uint r = x.i + 0x7fffu + ((x.i >> 16) & 1u);
    return (ushort)(r >> 16);
}

// async global->LDS, 16B per lane. LDS dest is wave-uniform base + lane*16.
__device__ __forceinline__ void gl_lds16(const void* g, void* l) {
    __builtin_amdgcn_global_load_lds(
        (const __attribute__((address_space(1))) unsigned int*)g,
        (__attribute__((address_space(3))) unsigned int*)l, 16, 0, 0);
}

__device__ __forceinline__ float block_sum(float v, float* s4) {
    #pragma unroll
    for (int off = 32; off; off >>= 1) v += __shfl_down(v, off);
    __syncthreads();
    if ((threadIdx.x & 63) == 0) s4[threadIdx.x >> 6] = v;
    __syncthreads();
    return s4[0] + s4[1] + s4[2] + s4[3];
}

// ---------------- weight f32 -> bf16 streaming convert ----------------
__global__ __launch_bounds__(256)
void convert_kernel(const float* __restrict__ src, ushort* __restrict__ dst, int n8) {
    int i = blockIdx.x * 256 + threadIdx.x;
    const int stride = gridDim.x * 256;
    for (; i < n8; i += stride) {
        const float* p = src + (size_t)i * 8;
        float4 a = *(const float4*)p;
        float4 b = *(const float4*)(p + 4);
        ushort o[8] = { f2bf(a.x), f2bf(a.y), f2bf(a.z), f2bf(a.w),
                        f2bf(b.x), f2bf(b.y), f2bf(b.z), f2bf(b.w) };
        *(s16x8*)(dst + (size_t)i * 8) = *(s16x8*)o;
    }
}

// ---------------- Router: LN stats, norm->bf16, logits, softmax, top-2 ----------------
__global__ __launch_bounds__(256)
void router_kernel(const float* __restrict__ x, const float* __restrict__ gate_w,
                   ushort* __restrict__ norm, float* __restrict__ scores,
                   int* __restrict__ cnt, int* __restrict__ lists, float* __restrict__ gates) {
    __shared__ float s4[4];
    const int n = blockIdx.x, tid = threadIdx.x;
    const float* xr = x + (size_t)n * DMODEL;
    float4 v = *(const float4*)(xr + tid * 4);

    float tot = block_sum(v.x + v.y + v.z + v.w, s4);
    float mu = tot * (1.0f / DMODEL);
    float d0 = v.x - mu, d1 = v.y - mu, d2 = v.z - mu, d3 = v.w - mu;
    float var = block_sum(d0 * d0 + d1 * d1 + d2 * d2 + d3 * d3, s4) * (1.0f / DMODEL);
    float rstd = rsqrtf(var + 1e-6f);

    ushort nb[4] = { f2bf(d0 * rstd), f2bf(d1 * rstd), f2bf(d2 * rstd), f2bf(d3 * rstd) };
    *(uint2*)(norm + (size_t)n * DMODEL + tid * 4) = *(uint2*)nb;

    float lg[NEXP];
    #pragma unroll
    for (int e = 0; e < NEXP; ++e) {
        float4 g = *(const float4*)(gate_w + (size_t)e * DMODEL + tid * 4);
        lg[e] = v.x * g.x + v.y * g.y + v.z * g.z + v.w * g.w;
    }
    #pragma unroll
    for (int e = 0; e < NEXP; ++e) lg[e] = block_sum(lg[e], s4);

    if (tid == 0) {
        float m = lg[0];
        #pragma unroll
        for (int e = 1; e < NEXP; ++e) m = fmaxf(m, lg[e]);
        float ex[NEXP], Z = 0.f;
        #pragma unroll
        for (int e = 0; e < NEXP; ++e) { ex[e] = expf(lg[e] - m); Z += ex[e]; }
        float inv = 1.0f / Z;
        float sc[NEXP];
        #pragma unroll
        for (int e = 0; e < NEXP; ++e) { sc[e] = ex[e] * inv; scores[n * NEXP + e] = sc[e]; }
        int i1 = 0;
        #pragma unroll
        for (int e = 1; e < NEXP; ++e) if (sc[e] > sc[i1]) i1 = e;
        int i2 = (i1 == 0) ? 1 : 0;
        #pragma unroll
        for (int e = 0; e < NEXP; ++e) if (e != i1 && sc[e] > sc[i2]) i2 = e;
        int s1 = atomicAdd(&cnt[i1], 1);
        lists[i1 * NMAX + s1] = n; gates[i1 * NMAX + s1] = sc[i1];
        int s2 = atomicAdd(&cnt[i2], 1);
        lists[i2 * NMAX + s2] = n; gates[i2 * NMAX + s2] = sc[i2];
    }
}

// ---------------- Prep: aux loss + exclusive scan of counts ----------------
__global__ __launch_bounds__(256)
void prep_kernel(const float* __restrict__ scores, const int* __restrict__ cnt,
                 int* __restrict__ offs, float* __restrict__ aux_out) {
    __shared__ float s4[4];
    __shared__ float imp[NEXP];
    float part[NEXP] = {};
    for (int i = threadIdx.x; i < N_TOK; i += 256) {
        #pragma unroll
        for (int e = 0; e < NEXP; ++e) part[e] += scores[i * NEXP + e];
    }
    #pragma unroll
    for (int e = 0; e < NEXP; ++e) {
        float s = block_sum(part[e], s4);
        if (threadIdx.x == 0) imp[e] = s;
    }
    __syncthreads();
    if (threadIdx.x == 0) {
        float aux = 0.f; int run = 0;
        #pragma unroll
        for (int e = 0; e < NEXP; ++e) {
            aux += imp[e] * (float)cnt[e];
            offs[e] = run; run += cnt[e];
        }
        aux_out[0] = aux * (float)NEXP / ((float)N_TOK * (float)N_TOK);
    }
}

// ---------------- Gather: A1[row] = norm[token]*ln_g[e] + ln_b[e] (bf16, grouped) -----
__global__ __launch_bounds__(256)
void gather_kernel(const ushort* __restrict__ norm, const float* __restrict__ ln_g,
                   const float* __restrict__ ln_b, const int* __restrict__ offs,
                   const int* __restrict__ lists, ushort* __restrict__ A1) {
    const int r = blockIdx.x;
    int e = 0;
    #pragma unroll
    for (int k = 1; k < NEXP; ++k) if (r >= offs[k]) e = k;
    const int slot = r - offs[e];
    const int token = lists[e * NMAX + slot];
    const int t4 = threadIdx.x * 4;
    uint2 nbv = *(const uint2*)(norm + (size_t)token * DMODEL + t4);
    ushort ns[4]; *(uint2*)ns = nbv;
    float4 gv = *(const float4*)(ln_g + (size_t)e * DMODEL + t4);
    float4 bv = *(const float4*)(ln_b + (size_t)e * DMODEL + t4);
    ushort ob[4] = { f2bf(bf2f(ns[0]) * gv.x + bv.x), f2bf(bf2f(ns[1]) * gv.y + bv.y),
                     f2bf(bf2f(ns[2]) * gv.z + bv.z), f2bf(bf2f(ns[3]) * gv.w + bv.w) };
    *(uint2*)(A1 + (size_t)r * DMODEL + t4) = *(uint2*)ob;
}

// ---------------- GEMM1: h = relu(A1 @ wc1^T + b1), grouped per expert ----------------
__global__ __launch_bounds__(256)
void gemm1_kernel(const ushort* __restrict__ A1, const ushort* __restrict__ wc1,
                  const float* __restrict__ b1, const int* __restrict__ cnt,
                  const int* __restrict__ offs, ushort* __restrict__ h) {
    __shared__ ushort As[BM * BK];
    __shared__ ushort Ws[BN * BK];
    const int nwg = gridDim.x;                 // 4096
    const int q = nwg >> 3;
    const int logical = ((int)blockIdx.x & 7) * q + ((int)blockIdx.x >> 3);
    const int mt = logical & (MT_MAX - 1);     // mt fastest -> same (e,nt) on one XCD
    const int g = logical >> 4;                // [0,256)
    const int nt = g & 31;
    const int e = g >> 5;
    const int M = cnt[e];
    if (mt * BM >= M) return;
    const int base = offs[e];

    const int tid = threadIdx.x, lane = tid & 63, wave = tid >> 6;
    const int wm = (wave & 1) * 64, wn = (wave >> 1) * 64;
    const int trow = lane >> 3, tcol = (lane & 7) * 8;

    const ushort* Ag = A1 + (size_t)(base + mt * BM) * DMODEL + tcol;
    const ushort* Wg = wc1 + ((size_t)e * FFDIM + nt * BN) * DMODEL + tcol;

    f32x4 acc[4][4] = {};

    for (int kt = 0; kt < DMODEL / BK; ++kt) {
        const int k0 = kt * BK;
        #pragma unroll
        for (int i = 0; i < 4; ++i) {
            const int c = wave * 4 + i;
            const int r = c * 8 + trow;
            gl_lds16(Ag + (size_t)r * DMODEL + k0, &As[c * 512]);
            gl_lds16(Wg + (size_t)r * DMODEL + k0, &Ws[c * 512]);
        }
        __syncthreads();
        #pragma unroll
        for (int kk = 0; kk < BK; kk += 32) {
            s16x8 af[4], bfr[4];
            #pragma unroll
            for (int mi = 0; mi < 4; ++mi)
                af[mi] = *(const s16x8*)&As[(wm + mi * 16 + (lane & 15)) * BK + kk + (lane >> 4) * 8];
            #pragma unroll
            for (int ni = 0; ni < 4; ++ni)
                bfr[ni] = *(const s16x8*)&Ws[(wn + ni * 16 + (lane & 15)) * BK + kk + (lane >> 4) * 8];
            #pragma unroll
            for (int mi = 0; mi < 4; ++mi)
                #pragma unroll
                for (int ni = 0; ni < 4; ++ni)
                    acc[mi][ni] = __builtin_amdgcn_mfma_f32_16x16x32_bf16(af[mi], bfr[ni], acc[mi][ni], 0, 0, 0);
        }
        __syncthreads();
    }
    #pragma unroll
    for (int ni = 0; ni < 4; ++ni) {
        const int nn = nt * BN + wn + ni * 16 + (lane & 15);
        const float b1v = b1[(size_t)e * FFDIM + nn];
        #pragma unroll
        for (int mi = 0; mi < 4; ++mi)
            #pragma unroll
            for (int r = 0; r < 4; ++r) {
                const int slot = mt * BM + wm + mi * 16 + ((lane >> 4) << 2) + r;
                if (slot < M)
                    h[(size_t)(base + slot) * FFDIM + nn] = f2bf(fmaxf(acc[mi][ni][r] + b1v, 0.f));
            }
    }
}

// ---------------- GEMM2 (split-K): out += g*(h @ wc2^T + b2 + x_skip) ----------------
__global__ __launch_bounds__(256)
void gemm2_kernel(const ushort* __restrict__ h, const ushort* __restrict__ wc2,
                  const float* __restrict__ b2, const float* __restrict__ x,
                  const int* __restrict__ cnt, const int* __restrict__ offs,
                  const int* __restrict__ lists, const float* __restrict__ gates,
                  float* __restrict__ out) {
    __shared__ ushort As[BM * BK];
    __shared__ ushort Ws[BN * BK];
    const int nwg = gridDim.x;                 // 4096
    const int q = nwg >> 3;
    const int logical = ((int)blockIdx.x & 7) * q + ((int)blockIdx.x >> 3);
    const int mt = logical & (MT_MAX - 1);
    const int kb = (logical >> 4) & (KSPL - 1);
    const int g = logical >> 6;                // [0,64)
    const int nt = g & 7;
    const int e = g >> 3;
    const int M = cnt[e];
    if (mt * BM >= M) return;
    const int base = offs[e];

    const int tid = threadIdx.x, lane = tid & 63, wave = tid >> 6;
    const int wm = (wave & 1) * 64, wn = (wave >> 1) * 64;
    const int trow = lane >> 3, tcol = (lane & 7) * 8;

    const ushort* Ag = h + (size_t)(base + mt * BM) * FFDIM + tcol;
    const ushort* Wg = wc2 + ((size_t)e * DMODEL + nt * BN) * FFDIM + tcol;

    f32x4 acc[4][4] = {};
    const int KSTEPS = FFDIM / BK / KSPL;      // 16

    for (int kt = kb * KSTEPS; kt < (kb + 1) * KSTEPS; ++kt) {
        const int k0 = kt * BK;
        #pragma unroll
        for (int i = 0; i < 4; ++i) {
            const int c = wave * 4 + i;
            const int r = c * 8 + trow;
            gl_lds16(Ag + (size_t)r * FFDIM + k0, &As[c * 512]);
            gl_lds16(Wg + (size_t)r * FFDIM + k0, &Ws[c * 512]);
        }
        __syncthreads();
        #pragma unroll
        for (int kk = 0; kk < BK; kk += 32) {
            s16x8 af[4], bfr[4];
            #pragma unroll
            for (int mi = 0; mi < 4; ++mi)
                af[mi] = *(const s16x8*)&As[(wm + mi * 16 + (lane & 15)) * BK + kk + (lane >> 4) * 8];
            #pragma unroll
            for (int ni = 0; ni < 4; ++ni)
                bfr[ni] = *(const s16x8*)&Ws[(wn + ni * 16 + (lane & 15)) * BK + kk + (lane >> 4) * 8];
            #pragma unroll
            for (int mi = 0; mi < 4; ++mi)
                #pragma unroll
                for (int ni = 0; ni < 4; ++ni)
                    acc[mi][ni] = __builtin_amdgcn_mfma_f32_16x16x32_bf16(af[mi], bfr[ni], acc[mi][ni], 0, 0, 0);
        }
        __syncthreads();
    }
    #pragma unroll
    for (int ni = 0; ni < 4; ++ni) {
        const int nn = nt * BN + wn + ni * 16 + (lane & 15);
        const float b2v = b2[(size_t)e * DMODEL + nn];
        #pragma unroll
        for (int mi = 0; mi < 4; ++mi)
            #pragma unroll
            for (int r = 0; r < 4; ++r) {
                const int slot = mt * BM + wm + mi * 16 + ((lane >> 4) << 2) + r;
                if (slot < M) {
                    const int token = lists[e * NMAX + slot];
                    const float gt = gates[e * NMAX + slot];
                    float val = gt * acc[mi][ni][r];
                    if (kb == 0) val += gt * (b2v + x[(size_t)token * DMODEL + nn]);
                    atomicAdd(out + (size_t)token * DMODEL + nn, val);
                }
            }
    }
}

extern "C" void kernel_launch(void* const* d_in, const int* in_sizes, int n_in,
                              void* d_out, int out_size, void* d_ws, size_t ws_size,
                              hipStream_t stream) {
    const float* x      = (const float*)d_in[0];
    const float* gate_w = (const float*)d_in[1];
    const float* ln_g   = (const float*)d_in[2];
    const float* ln_b   = (const float*)d_in[3];
    const float* w1     = (const float*)d_in[4];
    const float* b1     = (const float*)d_in[5];
    const float* w2     = (const float*)d_in[6];
    const float* b2     = (const float*)d_in[7];
    float* out = (float*)d_out;

    char* w = (char*)d_ws;
    int*    cnt    = (int*)(w + 0);
    int*    offs   = (int*)(w + 64);
    int*    lists  = (int*)(w + 1024);                    // 64 KB
    float*  gates  = (float*)(w + 66560);                 // 64 KB
    float*  scores = (float*)(w + 132096);                // 64 KB
    ushort* norm   = (ushort*)(w + 197632);               // 4 MB
    ushort* A1     = (ushort*)(w + 4391936);              // 8.65 MB (ROWS_PAD x D)
    ushort* h      = (ushort*)(w + 13042688);             // 34.6 MB (ROWS_PAD x FF)
    ushort* wc1    = (ushort*)(w + 47645696);             // 67.1 MB
    ushort* wc2    = (ushort*)(w + 114754560);            // 67.1 MB  (end ~182 MB)

    hipMemsetAsync(d_out, 0, (size_t)out_size * sizeof(float), stream);
    hipMemsetAsync(cnt, 0, 64, stream);

    convert_kernel<<<4096, 256, 0, stream>>>(w1, wc1, NEXP * FFDIM * DMODEL / 8);
    convert_kernel<<<4096, 256, 0, stream>>>(w2, wc2, NEXP * FFDIM * DMODEL / 8);
    router_kernel<<<N_TOK, 256, 0, stream>>>(x, gate_w, norm, scores, cnt, lists, gates);
    prep_kernel<<<1, 256, 0, stream>>>(scores, cnt, offs, out + (size_t)N_TOK * DMODEL);
    gather_kernel<<<ROWS, 256, 0, stream>>>(norm, ln_g, ln_b, offs, lists, A1);
    gemm1_kernel<<<(FFDIM / BN) * MT_MAX * NEXP, 256, 0, stream>>>(A1, wc1, b1, cnt, offs, h);
    gemm2_kernel<<<(DMODEL / BN) * MT_MAX * NEXP * KSPL, 256, 0, stream>>>(
        h, wc2, b2, x, cnt, offs, lists, gates, out);
}

// Round 3
// 405.040 us; speedup vs baseline: 1.2117x; 1.2117x over previous
//
#include <hip/hip_runtime.h>

#define N_TOK 2048
#define DMODEL 1024
#define NEXP 8
#define FFDIM 4096
#define NMAX 2048
#define ROWS 4096

#define BM 128
#define BN 128
#define BK 64
#define MT_MAX 16
#define KSPL 4

typedef __attribute__((ext_vector_type(8))) short s16x8;
typedef __attribute__((ext_vector_type(4))) float f32x4;

__device__ __forceinline__ float bf2f(ushort u) {
    union { uint i; float f; } x; x.i = ((uint)u) << 16; return x.f;
}
__device__ __forceinline__ ushort f2bf(float f) {
    union { float f; uint i; } x; x.f = f;
    uint r = x.i + 0x7fffu + ((x.i >> 16) & 1u);
    return (ushort)(r >> 16);
}

__device__ __forceinline__ void gl_lds16(const void* g, void* l) {
    __builtin_amdgcn_global_load_lds(
        (const __attribute__((address_space(1))) unsigned int*)g,
        (__attribute__((address_space(3))) unsigned int*)l, 16, 0, 0);
}

__device__ __forceinline__ float block_sum(float v, float* s4) {
    #pragma unroll
    for (int off = 32; off; off >>= 1) v += __shfl_down(v, off);
    __syncthreads();
    if ((threadIdx.x & 63) == 0) s4[threadIdx.x >> 6] = v;
    __syncthreads();
    return s4[0] + s4[1] + s4[2] + s4[3];
}

// ---------------- Router ----------------
__global__ __launch_bounds__(256)
void router_kernel(const float* __restrict__ x, const float* __restrict__ gate_w,
                   ushort* __restrict__ norm, float* __restrict__ scores,
                   int* __restrict__ cnt, int* __restrict__ lists,
                   int4* __restrict__ info, float2* __restrict__ gpair) {
    __shared__ float s4[4];
    const int n = blockIdx.x, tid = threadIdx.x;
    const float* xr = x + (size_t)n * DMODEL;
    float4 v = *(const float4*)(xr + tid * 4);

    float tot = block_sum(v.x + v.y + v.z + v.w, s4);
    float mu = tot * (1.0f / DMODEL);
    float d0 = v.x - mu, d1 = v.y - mu, d2 = v.z - mu, d3 = v.w - mu;
    float var = block_sum(d0 * d0 + d1 * d1 + d2 * d2 + d3 * d3, s4) * (1.0f / DMODEL);
    float rstd = rsqrtf(var + 1e-6f);

    ushort nb[4] = { f2bf(d0 * rstd), f2bf(d1 * rstd), f2bf(d2 * rstd), f2bf(d3 * rstd) };
    *(uint2*)(norm + (size_t)n * DMODEL + tid * 4) = *(uint2*)nb;

    float lg[NEXP];
    #pragma unroll
    for (int e = 0; e < NEXP; ++e) {
        float4 g = *(const float4*)(gate_w + (size_t)e * DMODEL + tid * 4);
        lg[e] = v.x * g.x + v.y * g.y + v.z * g.z + v.w * g.w;
    }
    #pragma unroll
    for (int e = 0; e < NEXP; ++e) lg[e] = block_sum(lg[e], s4);

    if (tid == 0) {
        float m = lg[0];
        #pragma unroll
        for (int e = 1; e < NEXP; ++e) m = fmaxf(m, lg[e]);
        float ex[NEXP], Z = 0.f;
        #pragma unroll
        for (int e = 0; e < NEXP; ++e) { ex[e] = expf(lg[e] - m); Z += ex[e]; }
        float inv = 1.0f / Z;
        float sc[NEXP];
        #pragma unroll
        for (int e = 0; e < NEXP; ++e) { sc[e] = ex[e] * inv; scores[n * NEXP + e] = sc[e]; }
        int i1 = 0;
        #pragma unroll
        for (int e = 1; e < NEXP; ++e) if (sc[e] > sc[i1]) i1 = e;
        int i2 = (i1 == 0) ? 1 : 0;
        #pragma unroll
        for (int e = 0; e < NEXP; ++e) if (e != i1 && sc[e] > sc[i2]) i2 = e;
        int s1 = atomicAdd(&cnt[i1], 1);
        lists[i1 * NMAX + s1] = n;
        int s2 = atomicAdd(&cnt[i2], 1);
        lists[i2 * NMAX + s2] = n;
        info[n] = make_int4(i1, s1, i2, s2);
        gpair[n] = make_float2(sc[i1], sc[i2]);
    }
}

// ---------------- Prep: aux loss + exclusive scan ----------------
__global__ __launch_bounds__(256)
void prep_kernel(const float* __restrict__ scores, const int* __restrict__ cnt,
                 int* __restrict__ offs, float* __restrict__ aux_out) {
    __shared__ float s4[4];
    __shared__ float imp[NEXP];
    float part[NEXP] = {};
    for (int i = threadIdx.x; i < N_TOK; i += 256) {
        #pragma unroll
        for (int e = 0; e < NEXP; ++e) part[e] += scores[i * NEXP + e];
    }
    #pragma unroll
    for (int e = 0; e < NEXP; ++e) {
        float s = block_sum(part[e], s4);
        if (threadIdx.x == 0) imp[e] = s;
    }
    __syncthreads();
    if (threadIdx.x == 0) {
        float aux = 0.f; int run = 0;
        #pragma unroll
        for (int e = 0; e < NEXP; ++e) {
            aux += imp[e] * (float)cnt[e];
            offs[e] = run; run += cnt[e];
        }
        aux_out[0] = aux * (float)NEXP / ((float)N_TOK * (float)N_TOK);
    }
}

// ---------------- Gather: A1[row] = norm[token]*ln_g[e] + ln_b[e] ----------------
__global__ __launch_bounds__(256)
void gather_kernel(const ushort* __restrict__ norm, const float* __restrict__ ln_g,
                   const float* __restrict__ ln_b, const int* __restrict__ offs,
                   const int* __restrict__ lists, ushort* __restrict__ A1) {
    const int r = blockIdx.x;
    int e = 0;
    #pragma unroll
    for (int k = 1; k < NEXP; ++k) if (r >= offs[k]) e = k;
    const int slot = r - offs[e];
    const int token = lists[e * NMAX + slot];
    const int t4 = threadIdx.x * 4;
    uint2 nbv = *(const uint2*)(norm + (size_t)token * DMODEL + t4);
    ushort ns[4]; *(uint2*)ns = nbv;
    float4 gv = *(const float4*)(ln_g + (size_t)e * DMODEL + t4);
    float4 bv = *(const float4*)(ln_b + (size_t)e * DMODEL + t4);
    ushort ob[4] = { f2bf(bf2f(ns[0]) * gv.x + bv.x), f2bf(bf2f(ns[1]) * gv.y + bv.y),
                     f2bf(bf2f(ns[2]) * gv.z + bv.z), f2bf(bf2f(ns[3]) * gv.w + bv.w) };
    *(uint2*)(A1 + (size_t)r * DMODEL + t4) = *(uint2*)ob;
}

// ---------------- GEMM1: h = relu(A1 @ w1^T + b1) ----------------
__global__ __launch_bounds__(256, 2)
void gemm1_kernel(const ushort* __restrict__ A1, const float* __restrict__ w1,
                  const float* __restrict__ b1, const int* __restrict__ cnt,
                  const int* __restrict__ offs, ushort* __restrict__ h) {
    __shared__ ushort As[2][BM * BK];
    __shared__ ushort Ws[2][BN * BK];
    const int q = (int)gridDim.x >> 3;
    const int logical = ((int)blockIdx.x & 7) * q + ((int)blockIdx.x >> 3);
    const int mt = logical & (MT_MAX - 1);
    const int g = logical >> 4;
    const int nt = g & 31;
    const int e = g >> 5;
    const int M = cnt[e];
    if (mt * BM >= M) return;
    const int base = offs[e];

    const int tid = threadIdx.x, lane = tid & 63, wave = tid >> 6;
    const int wm = (wave & 1) * 64, wn = (wave >> 1) * 64;
    const int trow = lane >> 3;
    const int scol = ((lane & 7) ^ trow) * 8;   // pre-swizzled source column

    const ushort* Agb = A1 + (size_t)(base + mt * BM) * DMODEL;
    const float*  Wg  = w1 + ((size_t)e * FFDIM + nt * BN) * DMODEL;

    f32x4 acc[4][4] = {};
    float4 wr[8];

    auto loadW = [&](int k0) {
        #pragma unroll
        for (int i = 0; i < 4; ++i) {
            int c = tid + 256 * i;
            const float* p = Wg + (size_t)(c >> 3) * DMODEL + k0 + (c & 7) * 8;
            wr[2 * i]     = *(const float4*)p;
            wr[2 * i + 1] = *(const float4*)(p + 4);
        }
    };
    auto writeW = [&](int b) {
        #pragma unroll
        for (int i = 0; i < 4; ++i) {
            int c = tid + 256 * i;
            int row = c >> 3, col8 = (c & 7) * 8;
            float4 a = wr[2 * i], d = wr[2 * i + 1];
            ushort o[8] = { f2bf(a.x), f2bf(a.y), f2bf(a.z), f2bf(a.w),
                            f2bf(d.x), f2bf(d.y), f2bf(d.z), f2bf(d.w) };
            *(s16x8*)&Ws[b][row * BK + (col8 ^ ((row & 7) << 3))] = *(s16x8*)o;
        }
    };
    auto stageA = [&](int k0, int b) {
        #pragma unroll
        for (int i = 0; i < 4; ++i) {
            int c = wave * 4 + i;
            gl_lds16(Agb + (size_t)(c * 8 + trow) * DMODEL + k0 + scol, &As[b][c * 512]);
        }
    };
    auto mfma_phase = [&](int b) {
        #pragma unroll
        for (int kk = 0; kk < BK; kk += 32) {
            const int cx = (kk + (lane >> 4) * 8) ^ ((lane & 7) << 3);
            s16x8 af[4], bfv[4];
            #pragma unroll
            for (int mi = 0; mi < 4; ++mi)
                af[mi] = *(const s16x8*)&As[b][(wm + mi * 16 + (lane & 15)) * BK + cx];
            #pragma unroll
            for (int ni = 0; ni < 4; ++ni)
                bfv[ni] = *(const s16x8*)&Ws[b][(wn + ni * 16 + (lane & 15)) * BK + cx];
            #pragma unroll
            for (int mi = 0; mi < 4; ++mi)
                #pragma unroll
                for (int ni = 0; ni < 4; ++ni)
                    acc[mi][ni] = __builtin_amdgcn_mfma_f32_16x16x32_bf16(af[mi], bfv[ni], acc[mi][ni], 0, 0, 0);
        }
    };

    loadW(0);
    stageA(0, 0);
    writeW(0);
    asm volatile("s_waitcnt vmcnt(0) lgkmcnt(0)" ::: "memory");
    __builtin_amdgcn_s_barrier();
    __builtin_amdgcn_sched_barrier(0);

    int buf = 0;
    const int KS = DMODEL / BK;
    for (int kt = 0; kt < KS; ++kt) {
        if (kt + 1 < KS) { loadW((kt + 1) * BK); stageA((kt + 1) * BK, buf ^ 1); }
        mfma_phase(buf);
        if (kt + 1 < KS) writeW(buf ^ 1);
        asm volatile("s_waitcnt vmcnt(0) lgkmcnt(0)" ::: "memory");
        __builtin_amdgcn_s_barrier();
        __builtin_amdgcn_sched_barrier(0);
        buf ^= 1;
    }

    #pragma unroll
    for (int ni = 0; ni < 4; ++ni) {
        const int nn = nt * BN + wn + ni * 16 + (lane & 15);
        const float b1v = b1[(size_t)e * FFDIM + nn];
        #pragma unroll
        for (int mi = 0; mi < 4; ++mi)
            #pragma unroll
            for (int r = 0; r < 4; ++r) {
                const int slot = mt * BM + wm + mi * 16 + ((lane >> 4) << 2) + r;
                if (slot < M)
                    h[(size_t)(base + slot) * FFDIM + nn] = f2bf(fmaxf(acc[mi][ni][r] + b1v, 0.f));
            }
    }
}

// ---------------- GEMM2 (split-K, no atomics): ypart[kb] = h @ w2^T ----------------
__global__ __launch_bounds__(256, 2)
void gemm2_kernel(const ushort* __restrict__ h, const float* __restrict__ w2,
                  const int* __restrict__ cnt, const int* __restrict__ offs,
                  float* __restrict__ ypart) {
    __shared__ ushort As[2][BM * BK];
    __shared__ ushort Ws[2][BN * BK];
    const int q = (int)gridDim.x >> 3;
    const int logical = ((int)blockIdx.x & 7) * q + ((int)blockIdx.x >> 3);
    const int mt = logical & (MT_MAX - 1);
    const int kb = (logical >> 4) & (KSPL - 1);
    const int g = logical >> 6;
    const int nt = g & 7;
    const int e = g >> 3;
    const int M = cnt[e];
    if (mt * BM >= M) return;
    const int base = offs[e];

    const int tid = threadIdx.x, lane = tid & 63, wave = tid >> 6;
    const int wm = (wave & 1) * 64, wn = (wave >> 1) * 64;
    const int trow = lane >> 3;
    const int scol = ((lane & 7) ^ trow) * 8;

    const ushort* Agb = h + (size_t)(base + mt * BM) * FFDIM;
    const float*  Wg  = w2 + ((size_t)e * DMODEL + nt * BN) * FFDIM;

    f32x4 acc[4][4] = {};
    float4 wr[8];

    auto loadW = [&](int k0) {
        #pragma unroll
        for (int i = 0; i < 4; ++i) {
            int c = tid + 256 * i;
            const float* p = Wg + (size_t)(c >> 3) * FFDIM + k0 + (c & 7) * 8;
            wr[2 * i]     = *(const float4*)p;
            wr[2 * i + 1] = *(const float4*)(p + 4);
        }
    };
    auto writeW = [&](int b) {
        #pragma unroll
        for (int i = 0; i < 4; ++i) {
            int c = tid + 256 * i;
            int row = c >> 3, col8 = (c & 7) * 8;
            float4 a = wr[2 * i], d = wr[2 * i + 1];
            ushort o[8] = { f2bf(a.x), f2bf(a.y), f2bf(a.z), f2bf(a.w),
                            f2bf(d.x), f2bf(d.y), f2bf(d.z), f2bf(d.w) };
            *(s16x8*)&Ws[b][row * BK + (col8 ^ ((row & 7) << 3))] = *(s16x8*)o;
        }
    };
    auto stageA = [&](int k0, int b) {
        #pragma unroll
        for (int i = 0; i < 4; ++i) {
            int c = wave * 4 + i;
            gl_lds16(Agb + (size_t)(c * 8 + trow) * FFDIM + k0 + scol, &As[b][c * 512]);
        }
    };
    auto mfma_phase = [&](int b) {
        #pragma unroll
        for (int kk = 0; kk < BK; kk += 32) {
            const int cx = (kk + (lane >> 4) * 8) ^ ((lane & 7) << 3);
            s16x8 af[4], bfv[4];
            #pragma unroll
            for (int mi = 0; mi < 4; ++mi)
                af[mi] = *(const s16x8*)&As[b][(wm + mi * 16 + (lane & 15)) * BK + cx];
            #pragma unroll
            for (int ni = 0; ni < 4; ++ni)
                bfv[ni] = *(const s16x8*)&Ws[b][(wn + ni * 16 + (lane & 15)) * BK + cx];
            #pragma unroll
            for (int mi = 0; mi < 4; ++mi)
                #pragma unroll
                for (int ni = 0; ni < 4; ++ni)
                    acc[mi][ni] = __builtin_amdgcn_mfma_f32_16x16x32_bf16(af[mi], bfv[ni], acc[mi][ni], 0, 0, 0);
        }
    };

    const int kt0 = kb * (FFDIM / BK / KSPL);
    const int KS = FFDIM / BK / KSPL;

    loadW(kt0 * BK);
    stageA(kt0 * BK, 0);
    writeW(0);
    asm volatile("s_waitcnt vmcnt(0) lgkmcnt(0)" ::: "memory");
    __builtin_amdgcn_s_barrier();
    __builtin_amdgcn_sched_barrier(0);

    int buf = 0;
    for (int kt = 0; kt < KS; ++kt) {
        if (kt + 1 < KS) { loadW((kt0 + kt + 1) * BK); stageA((kt0 + kt + 1) * BK, buf ^ 1); }
        mfma_phase(buf);
        if (kt + 1 < KS) writeW(buf ^ 1);
        asm volatile("s_waitcnt vmcnt(0) lgkmcnt(0)" ::: "memory");
        __builtin_amdgcn_s_barrier();
        __builtin_amdgcn_sched_barrier(0);
        buf ^= 1;
    }

    #pragma unroll
    for (int ni = 0; ni < 4; ++ni) {
        const int nn = nt * BN + wn + ni * 16 + (lane & 15);
        #pragma unroll
        for (int mi = 0; mi < 4; ++mi)
            #pragma unroll
            for (int r = 0; r < 4; ++r) {
                const int slot = mt * BM + wm + mi * 16 + ((lane >> 4) << 2) + r;
                if (slot < M)
                    ypart[((size_t)kb * ROWS + base + slot) * DMODEL + nn] = acc[mi][ni][r];
            }
    }
}

// ---------------- Combine: out[n] = sum_e g_e * (sum_kb ypart + b2[e] + x[n]) -------
__global__ __launch_bounds__(256)
void combine_kernel(const float* __restrict__ ypart, const float* __restrict__ b2,
                    const float* __restrict__ x, const int* __restrict__ offs,
                    const int4* __restrict__ info, const float2* __restrict__ gpair,
                    float* __restrict__ out) {
    const int n = blockIdx.x, d = threadIdx.x * 4;
    const int4 ii = info[n];
    const float2 g = gpair[n];
    const int r1 = offs[ii.x] + ii.y, r2 = offs[ii.z] + ii.w;
    f32x4 y1 = {}, y2 = {};
    #pragma unroll
    for (int kb = 0; kb < KSPL; ++kb) {
        y1 += *(const f32x4*)(ypart + ((size_t)kb * ROWS + r1) * DMODEL + d);
        y2 += *(const f32x4*)(ypart + ((size_t)kb * ROWS + r2) * DMODEL + d);
    }
    const f32x4 b21 = *(const f32x4*)(b2 + (size_t)ii.x * DMODEL + d);
    const f32x4 b22 = *(const f32x4*)(b2 + (size_t)ii.z * DMODEL + d);
    const f32x4 xv  = *(const f32x4*)(x + (size_t)n * DMODEL + d);
    f32x4 o = g.x * (y1 + b21 + xv) + g.y * (y2 + b22 + xv);
    *(f32x4*)(out + (size_t)n * DMODEL + d) = o;
}

extern "C" void kernel_launch(void* const* d_in, const int* in_sizes, int n_in,
                              void* d_out, int out_size, void* d_ws, size_t ws_size,
                              hipStream_t stream) {
    const float* x      = (const float*)d_in[0];
    const float* gate_w = (const float*)d_in[1];
    const float* ln_g   = (const float*)d_in[2];
    const float* ln_b   = (const float*)d_in[3];
    const float* w1     = (const float*)d_in[4];
    const float* b1     = (const float*)d_in[5];
    const float* w2     = (const float*)d_in[6];
    const float* b2     = (const float*)d_in[7];
    float* out = (float*)d_out;

    char* w = (char*)d_ws;
    int*    cnt    = (int*)(w + 0);
    int*    offs   = (int*)(w + 64);
    int*    lists  = (int*)(w + 1024);            // 64 KB
    float*  scores = (float*)(w + 66560);         // 64 KB
    int4*   info   = (int4*)(w + 132096);         // 32 KB
    float2* gpair  = (float2*)(w + 164864);       // 16 KB
    ushort* norm   = (ushort*)(w + 181248);       // 4 MB
    ushort* A1     = (ushort*)(w + 4375552);      // 8.4 MB
    ushort* h      = (ushort*)(w + 12764160);     // 33.6 MB
    float*  ypart  = (float*)(w + 46318592);      // 64 MB (KSPL x ROWS x D f32)

    hipMemsetAsync(cnt, 0, 64, stream);

    router_kernel<<<N_TOK, 256, 0, stream>>>(x, gate_w, norm, scores, cnt, lists, info, gpair);
    prep_kernel<<<1, 256, 0, stream>>>(scores, cnt, offs, out + (size_t)N_TOK * DMODEL);
    gather_kernel<<<ROWS, 256, 0, stream>>>(norm, ln_g, ln_b, offs, lists, A1);
    gemm1_kernel<<<(FFDIM / BN) * MT_MAX * NEXP, 256, 0, stream>>>(A1, w1, b1, cnt, offs, h);
    gemm2_kernel<<<(DMODEL / BN) * MT_MAX * NEXP * KSPL, 256, 0, stream>>>(h, w2, cnt, offs, ypart);
    combine_kernel<<<N_TOK, 256, 0, stream>>>(ypart, b2, x, offs, info, gpair, out);
}